// Round 3
// baseline (1732.148 us; speedup 1.0000x reference)
//
#include <hip/hip_runtime.h>
#include <hip/hip_bf16.h>

#define TTOK 2048
#define HDIM 1024
#define EXP  8
#define FDIM 2048

typedef __attribute__((ext_vector_type(8))) short short8;
typedef __attribute__((ext_vector_type(4))) float f32x4;
typedef __hip_bfloat16 bf16;

// workspace layout (bytes, all 256-aligned)
#define OFF_COUNTS 0
#define OFF_LISTS  256
#define OFF_WTS    (OFF_LISTS + EXP * TTOK * 4)          // 65792
#define OFF_XB     (OFF_WTS + 2 * TTOK * 4)              // 82176
#define OFF_ACT    (OFF_XB + TTOK * HDIM * 2)            // 4276480
#define OFF_OUTS   (OFF_ACT + 2 * TTOK * FDIM * 2)       // 21053696
// total end: 37830912 bytes (~36 MB)

__global__ void moe_init_kernel(int* counts) {
    if (threadIdx.x < EXP) counts[threadIdx.x] = 0;
}

// one wave per token: fp32 logits, top-2, softmax, append slots; also x -> bf16
__global__ __launch_bounds__(256)
void moe_router_kernel(const float* __restrict__ x, const float* __restrict__ rw,
                       int* __restrict__ counts, int* __restrict__ lists,
                       float* __restrict__ wts, bf16* __restrict__ xb) {
    const int lane = threadIdx.x & 63;
    const int t = blockIdx.x * 4 + (threadIdx.x >> 6);
    const float* xr = x + (size_t)t * HDIM;
    bf16* xbr = xb + (size_t)t * HDIM;
    float acc[EXP];
#pragma unroll
    for (int e = 0; e < EXP; ++e) acc[e] = 0.f;
    for (int h = lane; h < HDIM; h += 64) {
        float xv = xr[h];
        xbr[h] = __float2bfloat16(xv);
#pragma unroll
        for (int e = 0; e < EXP; ++e) acc[e] = fmaf(xv, rw[h * EXP + e], acc[e]);
    }
#pragma unroll
    for (int e = 0; e < EXP; ++e)
        for (int off = 32; off > 0; off >>= 1) acc[e] += __shfl_xor(acc[e], off, 64);
    if (lane == 0) {
        int i0 = 0; float v0 = acc[0];
#pragma unroll
        for (int e = 1; e < EXP; ++e) if (acc[e] > v0) { v0 = acc[e]; i0 = e; }
        int i1 = -1; float v1 = -3.4e38f;
#pragma unroll
        for (int e = 0; e < EXP; ++e) if (e != i0 && acc[e] > v1) { v1 = acc[e]; i1 = e; }
        float ex = expf(v1 - v0);             // v1 <= v0, stable
        float w0 = 1.f / (1.f + ex);
        float w1v = ex / (1.f + ex);
        wts[t * 2 + 0] = w0;
        wts[t * 2 + 1] = w1v;
        int p0 = atomicAdd(&counts[i0], 1);
        lists[i0 * TTOK + p0] = t * 2 + 0;
        int p1 = atomicAdd(&counts[i1], 1);
        lists[i1 * TTOK + p1] = t * 2 + 1;
    }
}

// gate/up GEMM: act[slot, f] = silu(x@w1) * (x@w3), bf16 out
// block: 256 thr, BM=64 slots, BN=128 f-cols, BK=32; waves 2x2, wave tile 32x64
__global__ __launch_bounds__(256)
void moe_up_kernel(const bf16* __restrict__ xb, const float* __restrict__ w1,
                   const float* __restrict__ w3, const int* __restrict__ counts,
                   const int* __restrict__ lists, bf16* __restrict__ act) {
    const int e = blockIdx.z;
    const int cnt = counts[e];
    const int tile0 = blockIdx.x * 64;
    if (tile0 >= cnt) return;
    const int f0 = blockIdx.y * 128;
    const int tid = threadIdx.x;
    const int lane = tid & 63, wid = tid >> 6;
    const int wm = wid >> 1, wn = wid & 1;

    __shared__ __align__(16) bf16 As[64][40];
    __shared__ __align__(16) bf16 B1s[128][40];
    __shared__ __align__(16) bf16 B3s[128][40];
    __shared__ int toks[64];
    __shared__ int srow[64];

    if (tid < 64) {
        int idx = tile0 + tid;
        int cl = idx < cnt ? idx : cnt - 1;
        int slot = lists[e * TTOK + cl];
        toks[tid] = slot >> 1;
        srow[tid] = (idx < cnt) ? slot : -1;
    }

    f32x4 accg[2][4], accu[2][4];
#pragma unroll
    for (int m = 0; m < 2; ++m)
#pragma unroll
        for (int n = 0; n < 4; ++n) {
            accg[m][n] = (f32x4){0.f, 0.f, 0.f, 0.f};
            accu[m][n] = (f32x4){0.f, 0.f, 0.f, 0.f};
        }

    const size_t eoff = (size_t)e * HDIM * FDIM;
    const int arow = tid >> 2, akg = tid & 3;

    for (int k0 = 0; k0 < HDIM; k0 += 32) {
        __syncthreads();
        // stage A: 64 rows x 32 k (bf16, gathered)
        float4 av = *(const float4*)(xb + (size_t)toks[arow] * HDIM + k0 + akg * 8);
        *(float4*)(&As[arow][akg * 8]) = av;
        // stage B1/B3: [32 k][128 f] fp32 -> bf16 transposed
#pragma unroll
        for (int p = 0; p < 4; ++p) {
            int pos = p * 1024 + tid * 4;
            int kk = pos >> 7, cc = pos & 127;
            const size_t gb = eoff + (size_t)(k0 + kk) * FDIM + f0 + cc;
            float4 v1 = *(const float4*)(w1 + gb);
            float4 v3 = *(const float4*)(w3 + gb);
            B1s[cc + 0][kk] = __float2bfloat16(v1.x);
            B1s[cc + 1][kk] = __float2bfloat16(v1.y);
            B1s[cc + 2][kk] = __float2bfloat16(v1.z);
            B1s[cc + 3][kk] = __float2bfloat16(v1.w);
            B3s[cc + 0][kk] = __float2bfloat16(v3.x);
            B3s[cc + 1][kk] = __float2bfloat16(v3.y);
            B3s[cc + 2][kk] = __float2bfloat16(v3.z);
            B3s[cc + 3][kk] = __float2bfloat16(v3.w);
        }
        __syncthreads();

        short8 af[2];
#pragma unroll
        for (int m = 0; m < 2; ++m)
            af[m] = *(const short8*)(&As[wm * 32 + m * 16 + (lane & 15)][(lane >> 4) * 8]);
        short8 b1f[4], b3f[4];
#pragma unroll
        for (int n = 0; n < 4; ++n) {
            int col = wn * 64 + n * 16 + (lane & 15);
            b1f[n] = *(const short8*)(&B1s[col][(lane >> 4) * 8]);
            b3f[n] = *(const short8*)(&B3s[col][(lane >> 4) * 8]);
        }
#pragma unroll
        for (int m = 0; m < 2; ++m)
#pragma unroll
            for (int n = 0; n < 4; ++n) {
                accg[m][n] = __builtin_amdgcn_mfma_f32_16x16x32_bf16(af[m], b1f[n], accg[m][n], 0, 0, 0);
                accu[m][n] = __builtin_amdgcn_mfma_f32_16x16x32_bf16(af[m], b3f[n], accu[m][n], 0, 0, 0);
            }
    }

    // epilogue: silu(g)*u -> act[slot, f]
#pragma unroll
    for (int m = 0; m < 2; ++m) {
        int rbase = wm * 32 + m * 16 + (lane >> 4) * 4;
#pragma unroll
        for (int r = 0; r < 4; ++r) {
            int slot = srow[rbase + r];
            if (slot < 0) continue;
#pragma unroll
            for (int n = 0; n < 4; ++n) {
                float g = accg[m][n][r], u = accu[m][n][r];
                float s = g / (1.f + expf(-g));
                int col = f0 + wn * 64 + n * 16 + (lane & 15);
                act[(size_t)slot * FDIM + col] = __float2bfloat16(s * u);
            }
        }
    }
}

// down GEMM: outs[slot, h] = wts[slot] * (act[slot,:] @ w2[e])
__global__ __launch_bounds__(256)
void moe_down_kernel(const bf16* __restrict__ act, const float* __restrict__ w2,
                     const int* __restrict__ counts, const int* __restrict__ lists,
                     const float* __restrict__ wts, float* __restrict__ outs) {
    const int e = blockIdx.z;
    const int cnt = counts[e];
    const int tile0 = blockIdx.x * 64;
    if (tile0 >= cnt) return;
    const int h0 = blockIdx.y * 128;
    const int tid = threadIdx.x;
    const int lane = tid & 63, wid = tid >> 6;
    const int wm = wid >> 1, wn = wid & 1;

    __shared__ __align__(16) bf16 As[64][40];
    __shared__ __align__(16) bf16 Bs[128][40];
    __shared__ int toks[64];
    __shared__ int srow[64];

    if (tid < 64) {
        int idx = tile0 + tid;
        int cl = idx < cnt ? idx : cnt - 1;
        int slot = lists[e * TTOK + cl];
        toks[tid] = slot;
        srow[tid] = (idx < cnt) ? slot : -1;
    }

    f32x4 acc[2][4];
#pragma unroll
    for (int m = 0; m < 2; ++m)
#pragma unroll
        for (int n = 0; n < 4; ++n) acc[m][n] = (f32x4){0.f, 0.f, 0.f, 0.f};

    const size_t eoff = (size_t)e * FDIM * HDIM;
    const int arow = tid >> 2, akg = tid & 3;

    for (int k0 = 0; k0 < FDIM; k0 += 32) {
        __syncthreads();
        float4 av = *(const float4*)(act + (size_t)toks[arow] * FDIM + k0 + akg * 8);
        *(float4*)(&As[arow][akg * 8]) = av;
#pragma unroll
        for (int p = 0; p < 4; ++p) {
            int pos = p * 1024 + tid * 4;
            int kk = pos >> 7, cc = pos & 127;
            float4 v2 = *(const float4*)(w2 + eoff + (size_t)(k0 + kk) * HDIM + h0 + cc);
            Bs[cc + 0][kk] = __float2bfloat16(v2.x);
            Bs[cc + 1][kk] = __float2bfloat16(v2.y);
            Bs[cc + 2][kk] = __float2bfloat16(v2.z);
            Bs[cc + 3][kk] = __float2bfloat16(v2.w);
        }
        __syncthreads();

        short8 af[2];
#pragma unroll
        for (int m = 0; m < 2; ++m)
            af[m] = *(const short8*)(&As[wm * 32 + m * 16 + (lane & 15)][(lane >> 4) * 8]);
        short8 bf[4];
#pragma unroll
        for (int n = 0; n < 4; ++n) {
            int col = wn * 64 + n * 16 + (lane & 15);
            bf[n] = *(const short8*)(&Bs[col][(lane >> 4) * 8]);
        }
#pragma unroll
        for (int m = 0; m < 2; ++m)
#pragma unroll
            for (int n = 0; n < 4; ++n)
                acc[m][n] = __builtin_amdgcn_mfma_f32_16x16x32_bf16(af[m], bf[n], acc[m][n], 0, 0, 0);
    }

#pragma unroll
    for (int m = 0; m < 2; ++m) {
        int rbase = wm * 32 + m * 16 + (lane >> 4) * 4;
#pragma unroll
        for (int r = 0; r < 4; ++r) {
            int slot = srow[rbase + r];
            if (slot < 0) continue;
            float w = wts[slot];
#pragma unroll
            for (int n = 0; n < 4; ++n) {
                int col = h0 + wn * 64 + n * 16 + (lane & 15);
                outs[(size_t)slot * HDIM + col] = acc[m][n][r] * w;
            }
        }
    }
}

// out[t] = outs[2t] + outs[2t+1]
__global__ __launch_bounds__(256)
void moe_combine_kernel(const float* __restrict__ outs, float* __restrict__ out) {
    int i = blockIdx.x * 256 + threadIdx.x;   // over T*H/4 float4s
    int t = i >> 8, c = i & 255;
    float4 a = ((const float4*)(outs + (size_t)(2 * t) * HDIM))[c];
    float4 b = ((const float4*)(outs + (size_t)(2 * t + 1) * HDIM))[c];
    float4 r;
    r.x = a.x + b.x; r.y = a.y + b.y; r.z = a.z + b.z; r.w = a.w + b.w;
    ((float4*)(out + (size_t)t * HDIM))[c] = r;
}

extern "C" void kernel_launch(void* const* d_in, const int* in_sizes, int n_in,
                              void* d_out, int out_size, void* d_ws, size_t ws_size,
                              hipStream_t stream) {
    const float* x  = (const float*)d_in[0];
    const float* rw = (const float*)d_in[1];
    const float* w1 = (const float*)d_in[2];
    const float* w3 = (const float*)d_in[3];
    const float* w2 = (const float*)d_in[4];
    float* out = (float*)d_out;
    char* ws = (char*)d_ws;

    int*   counts = (int*)(ws + OFF_COUNTS);
    int*   lists  = (int*)(ws + OFF_LISTS);
    float* wts    = (float*)(ws + OFF_WTS);
    bf16*  xb     = (bf16*)(ws + OFF_XB);
    bf16*  act    = (bf16*)(ws + OFF_ACT);
    float* outs   = (float*)(ws + OFF_OUTS);

    hipLaunchKernelGGL(moe_init_kernel, dim3(1), dim3(64), 0, stream, counts);
    hipLaunchKernelGGL(moe_router_kernel, dim3(TTOK / 4), dim3(256), 0, stream,
                       x, rw, counts, lists, wts, xb);
    hipLaunchKernelGGL(moe_up_kernel, dim3(32, FDIM / 128, EXP), dim3(256), 0, stream,
                       xb, w1, w3, counts, lists, act);
    hipLaunchKernelGGL(moe_down_kernel, dim3(32, HDIM / 128, EXP), dim3(256), 0, stream,
                       act, w2, counts, lists, wts, outs);
    hipLaunchKernelGGL(moe_combine_kernel, dim3(TTOK * HDIM / 4 / 256), dim3(256), 0, stream,
                       outs, out);
}

// Round 5
// 491.577 us; speedup vs baseline: 3.5237x; 3.5237x over previous
//
#include <hip/hip_runtime.h>
#include <hip/hip_bf16.h>

#define TTOK 2048
#define HDIM 1024
#define EXP  8
#define FDIM 2048

typedef __attribute__((ext_vector_type(8))) short short8;
typedef __attribute__((ext_vector_type(4))) float f32x4;
typedef __hip_bfloat16 bf16;

// async global->LDS, 16B per lane; LDS dest is wave-uniform base + lane*16
#define GLOAD16(gp, lp) __builtin_amdgcn_global_load_lds( \
    (const __attribute__((address_space(1))) void*)(gp),  \
    (__attribute__((address_space(3))) void*)(lp), 16, 0, 0)

#define MFMA16(a, b, c) __builtin_amdgcn_mfma_f32_16x16x32_bf16((a), (b), (c), 0, 0, 0)

// workspace layout (bytes, 256-aligned)
#define OFF_COUNTS 0
#define OFF_LISTS  256
#define OFF_WTS    (OFF_LISTS + EXP * TTOK * 4)            // 65792
#define OFF_XB     (OFF_WTS + 2 * TTOK * 4)                // 82176
#define OFF_ACT    (OFF_XB + TTOK * HDIM * 2)              // 4276480
#define OFF_OUTS   (OFF_ACT + 2 * TTOK * FDIM * 2)         // 21053696
#define OFF_WT1    (OFF_OUTS + 2 * TTOK * HDIM * 4)        // 37830912
#define OFF_WT3    (OFF_WT1 + EXP * HDIM * FDIM * 2)       // 71385344
#define OFF_WT2    (OFF_WT3 + EXP * HDIM * FDIM * 2)       // 104939776
// end: 138494208 (~132 MB)

__global__ void moe_init_kernel(int* counts) {
    if (threadIdx.x < EXP) counts[threadIdx.x] = 0;
}

// one wave per token: fp32 logits, top-2, softmax, append slots; also x -> bf16
__global__ __launch_bounds__(256)
void moe_router_kernel(const float* __restrict__ x, const float* __restrict__ rw,
                       int* __restrict__ counts, int* __restrict__ lists,
                       float* __restrict__ wts, bf16* __restrict__ xb) {
    const int lane = threadIdx.x & 63;
    const int t = blockIdx.x * 4 + (threadIdx.x >> 6);
    const float* xr = x + (size_t)t * HDIM;
    bf16* xbr = xb + (size_t)t * HDIM;
    float acc[EXP];
#pragma unroll
    for (int e = 0; e < EXP; ++e) acc[e] = 0.f;
    for (int h = lane; h < HDIM; h += 64) {
        float xv = xr[h];
        xbr[h] = __float2bfloat16(xv);
#pragma unroll
        for (int e = 0; e < EXP; ++e) acc[e] = fmaf(xv, rw[h * EXP + e], acc[e]);
    }
#pragma unroll
    for (int e = 0; e < EXP; ++e)
        for (int off = 32; off > 0; off >>= 1) acc[e] += __shfl_xor(acc[e], off, 64);
    if (lane == 0) {
        int i0 = 0; float v0 = acc[0];
#pragma unroll
        for (int e = 1; e < EXP; ++e) if (acc[e] > v0) { v0 = acc[e]; i0 = e; }
        int i1 = -1; float v1 = -3.4e38f;
#pragma unroll
        for (int e = 0; e < EXP; ++e) if (e != i0 && acc[e] > v1) { v1 = acc[e]; i1 = e; }
        float ex = expf(v1 - v0);             // v1 <= v0, stable
        float w0 = 1.f / (1.f + ex);
        float w1v = ex / (1.f + ex);
        wts[t * 2 + 0] = w0;
        wts[t * 2 + 1] = w1v;
        int p0 = atomicAdd(&counts[i0], 1);
        lists[i0 * TTOK + p0] = t * 2 + 0;
        int p1 = atomicAdd(&counts[i1], 1);
        lists[i1 * TTOK + p1] = t * 2 + 1;
    }
}

// transpose+convert: wt[e][c][r] = bf16(w[e][r][c]); 64x64 tiles via padded fp32 LDS
// grid (512, 3, EXP): y selects matrix. Conflict-free (2-way max) by odd-stride pad 65.
__global__ __launch_bounds__(256)
void moe_transpose_kernel(const float* __restrict__ w1, const float* __restrict__ w3,
                          const float* __restrict__ w2, bf16* __restrict__ wt1,
                          bf16* __restrict__ wt3, bf16* __restrict__ wt2) {
    const int e = blockIdx.z, m = blockIdx.y;
    const float* src; bf16* dst; int R, C;
    if (m == 0)      { src = w1; dst = wt1; R = HDIM; C = FDIM; }
    else if (m == 1) { src = w3; dst = wt3; R = HDIM; C = FDIM; }
    else             { src = w2; dst = wt2; R = FDIM; C = HDIM; }
    const int Ct = C >> 6;
    const int tr = blockIdx.x / Ct, tc = blockIdx.x - tr * Ct;
    const int r0 = tr << 6, c0 = tc << 6;
    src += (size_t)e * R * C;
    dst += (size_t)e * R * C;
    __shared__ float Ls[64][65];
    const int tid = threadIdx.x;
    const int rr = tid >> 4, cg = tid & 15;
#pragma unroll
    for (int i = 0; i < 4; ++i) {
        const int r = rr + i * 16;
        float4 v = *(const float4*)(src + (size_t)(r0 + r) * C + c0 + cg * 4);
        Ls[cg * 4 + 0][r] = v.x;
        Ls[cg * 4 + 1][r] = v.y;
        Ls[cg * 4 + 2][r] = v.z;
        Ls[cg * 4 + 3][r] = v.w;
    }
    __syncthreads();
    const int fr = tid >> 2, ch = tid & 3;
    bf16 tmp[16] __attribute__((aligned(16)));
#pragma unroll
    for (int j = 0; j < 16; ++j) tmp[j] = __float2bfloat16(Ls[fr][ch * 16 + j]);
    bf16* dp = dst + (size_t)(c0 + fr) * R + r0 + ch * 16;
    *(short8*)(dp)     = *(short8*)&tmp[0];
    *(short8*)(dp + 8) = *(short8*)&tmp[8];
}

// gate/up GEMM on pre-transposed bf16 weights. BM=64, BN=128, BK=64, 4 waves 2x2.
// Staging: global_load_lds w16, XOR-swizzle via pre-swizzled per-lane SOURCE (m173);
// reads: ds_read_b128 with chunk ^= (row&7) -> 2-way max conflicts.
__global__ __launch_bounds__(256)
void moe_up_kernel(const bf16* __restrict__ xb, const bf16* __restrict__ wt1,
                   const bf16* __restrict__ wt3, const int* __restrict__ counts,
                   const int* __restrict__ lists, bf16* __restrict__ act) {
    const int e = blockIdx.z;
    const int cnt = counts[e];
    const int tile0 = blockIdx.x * 64;
    if (tile0 >= cnt) return;
    const int f0 = blockIdx.y * 128;
    const int tid = threadIdx.x;
    const int lane = tid & 63, w = tid >> 6;
    const int wm = w >> 1, wn = w & 1;
    const int l15 = lane & 15, kg = lane >> 4;

    __shared__ __align__(16) bf16 As[64][64];
    __shared__ __align__(16) bf16 B1s[128][64];
    __shared__ __align__(16) bf16 B3s[128][64];
    __shared__ int toks[64];
    __shared__ int srow[64];

    if (tid < 64) {
        int idx = tile0 + tid;
        int cl = idx < cnt ? idx : cnt - 1;
        int slot = lists[e * TTOK + cl];
        toks[tid] = slot >> 1;
        srow[tid] = (idx < cnt) ? slot : -1;
    }
    __syncthreads();

    const int lr = lane >> 3, lc = lane & 7;   // staging sub-row / chunk
    const int sc = (lc ^ lr) * 8;              // swizzled source chunk (elements)
    const size_t ebase = (size_t)e * FDIM * HDIM;
    const size_t a0 = (size_t)toks[16 * w + lr] * HDIM + sc;
    const size_t a1 = (size_t)toks[16 * w + 8 + lr] * HDIM + sc;
    const size_t b0 = ebase + (size_t)(f0 + 32 * w + lr) * HDIM + sc;

    f32x4 accg[2][4], accu[2][4];
#pragma unroll
    for (int mf = 0; mf < 2; ++mf)
#pragma unroll
        for (int nf = 0; nf < 4; ++nf) {
            accg[mf][nf] = (f32x4){0.f, 0.f, 0.f, 0.f};
            accu[mf][nf] = (f32x4){0.f, 0.f, 0.f, 0.f};
        }

    for (int k0 = 0; k0 < HDIM; k0 += 64) {
        __syncthreads();
        GLOAD16(xb + a0 + k0, &As[16 * w][0]);
        GLOAD16(xb + a1 + k0, &As[16 * w + 8][0]);
#pragma unroll
        for (int j = 0; j < 4; ++j) {
            GLOAD16(wt1 + b0 + (size_t)j * 8 * HDIM + k0, &B1s[32 * w + 8 * j][0]);
            GLOAD16(wt3 + b0 + (size_t)j * 8 * HDIM + k0, &B3s[32 * w + 8 * j][0]);
        }
        __syncthreads();   // compiler drains vmcnt before barrier -> data ready

#pragma unroll
        for (int ks = 0; ks < 2; ++ks) {
            const int c = ((ks * 4 + kg) ^ (l15 & 7)) * 8;
            short8 af[2], b1f[4], b3f[4];
#pragma unroll
            for (int mf = 0; mf < 2; ++mf)
                af[mf] = *(const short8*)(&As[wm * 32 + mf * 16 + l15][c]);
#pragma unroll
            for (int nf = 0; nf < 4; ++nf) {
                const int col = wn * 64 + nf * 16 + l15;
                b1f[nf] = *(const short8*)(&B1s[col][c]);
                b3f[nf] = *(const short8*)(&B3s[col][c]);
            }
#pragma unroll
            for (int mf = 0; mf < 2; ++mf)
#pragma unroll
                for (int nf = 0; nf < 4; ++nf) {
                    accg[mf][nf] = MFMA16(af[mf], b1f[nf], accg[mf][nf]);
                    accu[mf][nf] = MFMA16(af[mf], b3f[nf], accu[mf][nf]);
                }
        }
    }

    // epilogue: silu(g)*u -> act[slot, f]
#pragma unroll
    for (int mf = 0; mf < 2; ++mf) {
        const int rbase = wm * 32 + mf * 16 + kg * 4;
#pragma unroll
        for (int r = 0; r < 4; ++r) {
            const int slot = srow[rbase + r];
            if (slot < 0) continue;
#pragma unroll
            for (int nf = 0; nf < 4; ++nf) {
                float g = accg[mf][nf][r], u = accu[mf][nf][r];
                float s = g / (1.f + expf(-g));
                act[(size_t)slot * FDIM + f0 + wn * 64 + nf * 16 + l15] = __float2bfloat16(s * u);
            }
        }
    }
}

// down GEMM: outs[slot, h] = wts[slot] * (act[slot,:] @ wt2[e][h,:]^T)
__global__ __launch_bounds__(256)
void moe_down_kernel(const bf16* __restrict__ act, const bf16* __restrict__ wt2,
                     const int* __restrict__ counts, const int* __restrict__ lists,
                     const float* __restrict__ wts, float* __restrict__ outs) {
    const int e = blockIdx.z;
    const int cnt = counts[e];
    const int tile0 = blockIdx.x * 64;
    if (tile0 >= cnt) return;
    const int h0 = blockIdx.y * 128;
    const int tid = threadIdx.x;
    const int lane = tid & 63, w = tid >> 6;
    const int wm = w >> 1, wn = w & 1;
    const int l15 = lane & 15, kg = lane >> 4;

    __shared__ __align__(16) bf16 As[64][64];
    __shared__ __align__(16) bf16 Bs[128][64];
    __shared__ int toks[64];
    __shared__ int srow[64];

    if (tid < 64) {
        int idx = tile0 + tid;
        int cl = idx < cnt ? idx : cnt - 1;
        int slot = lists[e * TTOK + cl];
        toks[tid] = slot;
        srow[tid] = (idx < cnt) ? slot : -1;
    }
    __syncthreads();

    const int lr = lane >> 3, lc = lane & 7;
    const int sc = (lc ^ lr) * 8;
    const size_t ebase = (size_t)e * FDIM * HDIM;
    const size_t a0 = (size_t)toks[16 * w + lr] * FDIM + sc;
    const size_t a1 = (size_t)toks[16 * w + 8 + lr] * FDIM + sc;
    const size_t b0 = ebase + (size_t)(h0 + 32 * w + lr) * FDIM + sc;

    f32x4 acc[2][4];
#pragma unroll
    for (int mf = 0; mf < 2; ++mf)
#pragma unroll
        for (int nf = 0; nf < 4; ++nf) acc[mf][nf] = (f32x4){0.f, 0.f, 0.f, 0.f};

    for (int k0 = 0; k0 < FDIM; k0 += 64) {
        __syncthreads();
        GLOAD16(act + a0 + k0, &As[16 * w][0]);
        GLOAD16(act + a1 + k0, &As[16 * w + 8][0]);
#pragma unroll
        for (int j = 0; j < 4; ++j)
            GLOAD16(wt2 + b0 + (size_t)j * 8 * FDIM + k0, &Bs[32 * w + 8 * j][0]);
        __syncthreads();

#pragma unroll
        for (int ks = 0; ks < 2; ++ks) {
            const int c = ((ks * 4 + kg) ^ (l15 & 7)) * 8;
            short8 af[2], bf[4];
#pragma unroll
            for (int mf = 0; mf < 2; ++mf)
                af[mf] = *(const short8*)(&As[wm * 32 + mf * 16 + l15][c]);
#pragma unroll
            for (int nf = 0; nf < 4; ++nf)
                bf[nf] = *(const short8*)(&Bs[wn * 64 + nf * 16 + l15][c]);
#pragma unroll
            for (int mf = 0; mf < 2; ++mf)
#pragma unroll
                for (int nf = 0; nf < 4; ++nf)
                    acc[mf][nf] = MFMA16(af[mf], bf[nf], acc[mf][nf]);
        }
    }

#pragma unroll
    for (int mf = 0; mf < 2; ++mf) {
        const int rbase = wm * 32 + mf * 16 + kg * 4;
#pragma unroll
        for (int r = 0; r < 4; ++r) {
            const int slot = srow[rbase + r];
            if (slot < 0) continue;
            const float wgt = wts[slot];
#pragma unroll
            for (int nf = 0; nf < 4; ++nf)
                outs[(size_t)slot * HDIM + h0 + wn * 64 + nf * 16 + l15] = acc[mf][nf][r] * wgt;
        }
    }
}

// out[t] = outs[2t] + outs[2t+1]
__global__ __launch_bounds__(256)
void moe_combine_kernel(const float* __restrict__ outs, float* __restrict__ out) {
    int i = blockIdx.x * 256 + threadIdx.x;   // over T*H/4 float4s
    int t = i >> 8, c = i & 255;
    float4 a = ((const float4*)(outs + (size_t)(2 * t) * HDIM))[c];
    float4 b = ((const float4*)(outs + (size_t)(2 * t + 1) * HDIM))[c];
    float4 r;
    r.x = a.x + b.x; r.y = a.y + b.y; r.z = a.z + b.z; r.w = a.w + b.w;
    ((float4*)(out + (size_t)t * HDIM))[c] = r;
}

extern "C" void kernel_launch(void* const* d_in, const int* in_sizes, int n_in,
                              void* d_out, int out_size, void* d_ws, size_t ws_size,
                              hipStream_t stream) {
    const float* x  = (const float*)d_in[0];
    const float* rw = (const float*)d_in[1];
    const float* w1 = (const float*)d_in[2];
    const float* w3 = (const float*)d_in[3];
    const float* w2 = (const float*)d_in[4];
    float* out = (float*)d_out;
    char* ws = (char*)d_ws;

    int*   counts = (int*)(ws + OFF_COUNTS);
    int*   lists  = (int*)(ws + OFF_LISTS);
    float* wts    = (float*)(ws + OFF_WTS);
    bf16*  xb     = (bf16*)(ws + OFF_XB);
    bf16*  act    = (bf16*)(ws + OFF_ACT);
    float* outs   = (float*)(ws + OFF_OUTS);
    bf16*  wt1    = (bf16*)(ws + OFF_WT1);
    bf16*  wt3    = (bf16*)(ws + OFF_WT3);
    bf16*  wt2    = (bf16*)(ws + OFF_WT2);

    hipLaunchKernelGGL(moe_init_kernel, dim3(1), dim3(64), 0, stream, counts);
    hipLaunchKernelGGL(moe_transpose_kernel, dim3(512, 3, EXP), dim3(256), 0, stream,
                       w1, w3, w2, wt1, wt3, wt2);
    hipLaunchKernelGGL(moe_router_kernel, dim3(TTOK / 4), dim3(256), 0, stream,
                       x, rw, counts, lists, wts, xb);
    hipLaunchKernelGGL(moe_up_kernel, dim3(32, FDIM / 128, EXP), dim3(256), 0, stream,
                       xb, wt1, wt3, counts, lists, act);
    hipLaunchKernelGGL(moe_down_kernel, dim3(32, HDIM / 128, EXP), dim3(256), 0, stream,
                       act, wt2, counts, lists, wts, outs);
    hipLaunchKernelGGL(moe_combine_kernel, dim3(TTOK * HDIM / 4 / 256), dim3(256), 0, stream,
                       outs, out);
}

// Round 7
// 402.643 us; speedup vs baseline: 4.3019x; 1.2209x over previous
//
#include <hip/hip_runtime.h>
#include <hip/hip_bf16.h>

#define TTOK 2048
#define HDIM 1024
#define EXP  8
#define FDIM 2048

typedef __attribute__((ext_vector_type(8))) short short8;
typedef __attribute__((ext_vector_type(4))) float f32x4;
typedef __hip_bfloat16 bf16;

// async global->LDS, 16B per lane; LDS dest is wave-uniform base + lane*16
#define GLOAD16(gp, lp) __builtin_amdgcn_global_load_lds( \
    (const __attribute__((address_space(1))) void*)(gp),  \
    (__attribute__((address_space(3))) void*)(lp), 16, 0, 0)

#define MFMA16(a, b, c) __builtin_amdgcn_mfma_f32_16x16x32_bf16((a), (b), (c), 0, 0, 0)

// workspace layout (bytes, 256-aligned)
#define OFF_COUNTS 0
#define OFF_LISTS  256
#define OFF_WTS    (OFF_LISTS + EXP * TTOK * 4)            // 65792
#define OFF_XB     (OFF_WTS + 2 * TTOK * 4)                // 82176
#define OFF_ACT    (OFF_XB + TTOK * HDIM * 2)              // 4276480
#define OFF_OUTS   (OFF_ACT + 2 * TTOK * FDIM * 2)         // 21053696
#define OFF_WT1    (OFF_OUTS + 2 * TTOK * HDIM * 4)        // 37830912
#define OFF_WT3    (OFF_WT1 + EXP * HDIM * FDIM * 2)       // 71385344
#define OFF_WT2    (OFF_WT3 + EXP * HDIM * FDIM * 2)       // 104939776
// end: 138494208 (~132 MB)

__global__ void moe_init_kernel(int* counts) {
    if (threadIdx.x < EXP) counts[threadIdx.x] = 0;
}

// one wave per token: fp32 logits, top-2, softmax, append slots; also x -> bf16
__global__ __launch_bounds__(256)
void moe_router_kernel(const float* __restrict__ x, const float* __restrict__ rw,
                       int* __restrict__ counts, int* __restrict__ lists,
                       float* __restrict__ wts, bf16* __restrict__ xb) {
    const int lane = threadIdx.x & 63;
    const int t = blockIdx.x * 4 + (threadIdx.x >> 6);
    const float* xr = x + (size_t)t * HDIM;
    bf16* xbr = xb + (size_t)t * HDIM;
    float acc[EXP];
#pragma unroll
    for (int e = 0; e < EXP; ++e) acc[e] = 0.f;
    for (int h = lane; h < HDIM; h += 64) {
        float xv = xr[h];
        xbr[h] = __float2bfloat16(xv);
#pragma unroll
        for (int e = 0; e < EXP; ++e) acc[e] = fmaf(xv, rw[h * EXP + e], acc[e]);
    }
#pragma unroll
    for (int e = 0; e < EXP; ++e)
        for (int off = 32; off > 0; off >>= 1) acc[e] += __shfl_xor(acc[e], off, 64);
    if (lane == 0) {
        int i0 = 0; float v0 = acc[0];
#pragma unroll
        for (int e = 1; e < EXP; ++e) if (acc[e] > v0) { v0 = acc[e]; i0 = e; }
        int i1 = -1; float v1 = -3.4e38f;
#pragma unroll
        for (int e = 0; e < EXP; ++e) if (e != i0 && acc[e] > v1) { v1 = acc[e]; i1 = e; }
        float ex = expf(v1 - v0);             // v1 <= v0, stable
        float w0 = 1.f / (1.f + ex);
        float w1v = ex / (1.f + ex);
        wts[t * 2 + 0] = w0;
        wts[t * 2 + 1] = w1v;
        int p0 = atomicAdd(&counts[i0], 1);
        lists[i0 * TTOK + p0] = t * 2 + 0;
        int p1 = atomicAdd(&counts[i1], 1);
        lists[i1 * TTOK + p1] = t * 2 + 1;
    }
}

// transpose+convert: wt[e][c][r] = bf16(w[e][r][c]); 64x64 tiles via padded fp32 LDS
__global__ __launch_bounds__(256)
void moe_transpose_kernel(const float* __restrict__ w1, const float* __restrict__ w3,
                          const float* __restrict__ w2, bf16* __restrict__ wt1,
                          bf16* __restrict__ wt3, bf16* __restrict__ wt2) {
    const int e = blockIdx.z, m = blockIdx.y;
    const float* src; bf16* dst; int R, C;
    if (m == 0)      { src = w1; dst = wt1; R = HDIM; C = FDIM; }
    else if (m == 1) { src = w3; dst = wt3; R = HDIM; C = FDIM; }
    else             { src = w2; dst = wt2; R = FDIM; C = HDIM; }
    const int Ct = C >> 6;
    const int tr = blockIdx.x / Ct, tc = blockIdx.x - tr * Ct;
    const int r0 = tr << 6, c0 = tc << 6;
    src += (size_t)e * R * C;
    dst += (size_t)e * R * C;
    __shared__ float Ls[64][65];
    const int tid = threadIdx.x;
    const int rr = tid >> 4, cg = tid & 15;
#pragma unroll
    for (int i = 0; i < 4; ++i) {
        const int r = rr + i * 16;
        float4 v = *(const float4*)(src + (size_t)(r0 + r) * C + c0 + cg * 4);
        Ls[cg * 4 + 0][r] = v.x;
        Ls[cg * 4 + 1][r] = v.y;
        Ls[cg * 4 + 2][r] = v.z;
        Ls[cg * 4 + 3][r] = v.w;
    }
    __syncthreads();
    const int fr = tid >> 2, ch = tid & 3;
    bf16 tmp[16] __attribute__((aligned(16)));
#pragma unroll
    for (int j = 0; j < 16; ++j) tmp[j] = __float2bfloat16(Ls[fr][ch * 16 + j]);
    bf16* dp = dst + (size_t)(c0 + fr) * R + r0 + ch * 16;
    *(short8*)(dp)     = *(short8*)&tmp[0];
    *(short8*)(dp + 8) = *(short8*)&tmp[8];
}

// gate/up GEMM: BM=128, BN=128, BK=64, 4 waves (2x2, wave-tile 64x64), 2-phase dbuf.
// Grid 1-D 1024: decoded so all m-blocks of one (f-tile,expert) B-panel share an XCD.
__global__ __launch_bounds__(256)
void moe_up_kernel(const bf16* __restrict__ xb, const bf16* __restrict__ wt1,
                   const bf16* __restrict__ wt3, const int* __restrict__ counts,
                   const int* __restrict__ lists, bf16* __restrict__ act) {
    const int b = blockIdx.x;
    const int xcd = b & 7, q = b >> 3;     // q 0..127
    const int pw = q >> 3, m = q & 7;      // pw 0..15
    const int p = pw * 8 + xcd;            // panel 0..127, xcd = p%8
    const int ft = p & 15, e = p >> 4;
    const int cnt = counts[e];
    const int tile0 = m * 128;
    if (tile0 >= cnt) return;
    const int f0 = ft * 128;

    const int tid = threadIdx.x;
    const int lane = tid & 63, w = tid >> 6;
    const int wm = w >> 1, wn = w & 1;
    const int l15 = lane & 15, kg = lane >> 4;
    const int lr = lane >> 3, lc = lane & 7;
    const int sc = (lc ^ lr) * 8;          // swizzled source chunk (elements)

    __shared__ __align__(16) bf16 As0[128][64], As1[128][64];
    __shared__ __align__(16) bf16 B1s0[128][64], B1s1[128][64];
    __shared__ __align__(16) bf16 B3s0[128][64], B3s1[128][64];
    __shared__ int toks[128];
    __shared__ int srow[128];

    if (tid < 128) {
        int idx = tile0 + tid;
        int cl = idx < cnt ? idx : cnt - 1;
        int slot = lists[e * TTOK + cl];
        toks[tid] = slot >> 1;
        srow[tid] = (idx < cnt) ? slot : -1;
    }
    __syncthreads();

    size_t aoff[4];
#pragma unroll
    for (int j = 0; j < 4; ++j)
        aoff[j] = (size_t)toks[32 * w + 8 * j + lr] * HDIM + sc;
    const size_t ebase = (size_t)e * FDIM * HDIM;
    const size_t boff = ebase + (size_t)(f0 + 32 * w + lr) * HDIM + sc;

    f32x4 accg[4][4], accu[4][4];
#pragma unroll
    for (int mf = 0; mf < 4; ++mf)
#pragma unroll
        for (int nf = 0; nf < 4; ++nf) {
            accg[mf][nf] = (f32x4){0.f, 0.f, 0.f, 0.f};
            accu[mf][nf] = (f32x4){0.f, 0.f, 0.f, 0.f};
        }

    auto stage = [&](int k0, bf16 (*A)[64], bf16 (*B1)[64], bf16 (*B3)[64]) {
#pragma unroll
        for (int j = 0; j < 4; ++j) {
            GLOAD16(xb + aoff[j] + k0, &A[32 * w + 8 * j][0]);
            GLOAD16(wt1 + boff + (size_t)(8 * j) * HDIM + k0, &B1[32 * w + 8 * j][0]);
            GLOAD16(wt3 + boff + (size_t)(8 * j) * HDIM + k0, &B3[32 * w + 8 * j][0]);
        }
    };
    auto compute = [&](bf16 (*A)[64], bf16 (*B1)[64], bf16 (*B3)[64]) {
#pragma unroll
        for (int ks = 0; ks < 2; ++ks) {
            const int c = ((ks * 4 + kg) ^ (l15 & 7)) * 8;
            short8 af[4], b1f[4], b3f[4];
#pragma unroll
            for (int i = 0; i < 4; ++i) {
                af[i]  = *(const short8*)(&A[wm * 64 + i * 16 + l15][c]);
                b1f[i] = *(const short8*)(&B1[wn * 64 + i * 16 + l15][c]);
                b3f[i] = *(const short8*)(&B3[wn * 64 + i * 16 + l15][c]);
            }
#pragma unroll
            for (int mf = 0; mf < 4; ++mf)
#pragma unroll
                for (int nf = 0; nf < 4; ++nf) {
                    accg[mf][nf] = MFMA16(af[mf], b1f[nf], accg[mf][nf]);
                    accu[mf][nf] = MFMA16(af[mf], b3f[nf], accu[mf][nf]);
                }
        }
    };

    stage(0, As0, B1s0, B3s0);
    __syncthreads();                          // drain prologue loads
    for (int k0 = 0; k0 < HDIM; k0 += 128) {
        if (k0 + 64 < HDIM) stage(k0 + 64, As1, B1s1, B3s1);
        compute(As0, B1s0, B3s0);
        __syncthreads();                      // drains prefetch vmcnt + protects overwrite
        if (k0 + 128 < HDIM) stage(k0 + 128, As0, B1s0, B3s0);
        compute(As1, B1s1, B3s1);
        __syncthreads();
    }

    // epilogue: silu(g)*u -> act[slot, f]
#pragma unroll
    for (int mf = 0; mf < 4; ++mf) {
        const int rbase = wm * 64 + mf * 16 + kg * 4;
#pragma unroll
        for (int r = 0; r < 4; ++r) {
            const int slot = srow[rbase + r];
            if (slot < 0) continue;
#pragma unroll
            for (int nf = 0; nf < 4; ++nf) {
                float g = accg[mf][nf][r], u = accu[mf][nf][r];
                float s = g / (1.f + expf(-g));
                act[(size_t)slot * FDIM + f0 + wn * 64 + nf * 16 + l15] = __float2bfloat16(s * u);
            }
        }
    }
}

// down GEMM: BM=128, BN=128, BK=64, 4 waves, 2-phase dbuf; outs = wts * (act @ wt2^T)
__global__ __launch_bounds__(256)
void moe_down_kernel(const bf16* __restrict__ act, const bf16* __restrict__ wt2,
                     const int* __restrict__ counts, const int* __restrict__ lists,
                     const float* __restrict__ wts, float* __restrict__ outs) {
    const int b = blockIdx.x;
    const int xcd = b & 7, q = b >> 3;     // q 0..63
    const int pw = q >> 3, m = q & 7;      // pw 0..7
    const int p = pw * 8 + xcd;            // panel 0..63
    const int ht = p & 7, e = p >> 3;
    const int cnt = counts[e];
    const int tile0 = m * 128;
    if (tile0 >= cnt) return;
    const int h0 = ht * 128;

    const int tid = threadIdx.x;
    const int lane = tid & 63, w = tid >> 6;
    const int wm = w >> 1, wn = w & 1;
    const int l15 = lane & 15, kg = lane >> 4;
    const int lr = lane >> 3, lc = lane & 7;
    const int sc = (lc ^ lr) * 8;

    __shared__ __align__(16) bf16 As0[128][64], As1[128][64];
    __shared__ __align__(16) bf16 Bs0[128][64], Bs1[128][64];
    __shared__ int toks[128];
    __shared__ int srow[128];

    if (tid < 128) {
        int idx = tile0 + tid;
        int cl = idx < cnt ? idx : cnt - 1;
        int slot = lists[e * TTOK + cl];
        toks[tid] = slot;
        srow[tid] = (idx < cnt) ? slot : -1;
    }
    __syncthreads();

    size_t aoff[4];
#pragma unroll
    for (int j = 0; j < 4; ++j)
        aoff[j] = (size_t)toks[32 * w + 8 * j + lr] * FDIM + sc;
    const size_t ebase = (size_t)e * FDIM * HDIM;
    const size_t boff = ebase + (size_t)(h0 + 32 * w + lr) * FDIM + sc;

    f32x4 acc[4][4];
#pragma unroll
    for (int mf = 0; mf < 4; ++mf)
#pragma unroll
        for (int nf = 0; nf < 4; ++nf) acc[mf][nf] = (f32x4){0.f, 0.f, 0.f, 0.f};

    auto stage = [&](int k0, bf16 (*A)[64], bf16 (*B)[64]) {
#pragma unroll
        for (int j = 0; j < 4; ++j) {
            GLOAD16(act + aoff[j] + k0, &A[32 * w + 8 * j][0]);
            GLOAD16(wt2 + boff + (size_t)(8 * j) * FDIM + k0, &B[32 * w + 8 * j][0]);
        }
    };
    auto compute = [&](bf16 (*A)[64], bf16 (*B)[64]) {
#pragma unroll
        for (int ks = 0; ks < 2; ++ks) {
            const int c = ((ks * 4 + kg) ^ (l15 & 7)) * 8;
            short8 af[4], bf[4];
#pragma unroll
            for (int i = 0; i < 4; ++i) {
                af[i] = *(const short8*)(&A[wm * 64 + i * 16 + l15][c]);
                bf[i] = *(const short8*)(&B[wn * 64 + i * 16 + l15][c]);
            }
#pragma unroll
            for (int mf = 0; mf < 4; ++mf)
#pragma unroll
                for (int nf = 0; nf < 4; ++nf)
                    acc[mf][nf] = MFMA16(af[mf], bf[nf], acc[mf][nf]);
        }
    };

    stage(0, As0, Bs0);
    __syncthreads();
    for (int k0 = 0; k0 < FDIM; k0 += 128) {
        if (k0 + 64 < FDIM) stage(k0 + 64, As1, Bs1);
        compute(As0, Bs0);
        __syncthreads();
        if (k0 + 128 < FDIM) stage(k0 + 128, As0, Bs0);
        compute(As1, Bs1);
        __syncthreads();
    }

#pragma unroll
    for (int mf = 0; mf < 4; ++mf) {
        const int rbase = wm * 64 + mf * 16 + kg * 4;
#pragma unroll
        for (int r = 0; r < 4; ++r) {
            const int slot = srow[rbase + r];
            if (slot < 0) continue;
            const float wgt = wts[slot];
#pragma unroll
            for (int nf = 0; nf < 4; ++nf)
                outs[(size_t)slot * HDIM + h0 + wn * 64 + nf * 16 + l15] = acc[mf][nf][r] * wgt;
        }
    }
}

// out[t] = outs[2t] + outs[2t+1]
__global__ __launch_bounds__(256)
void moe_combine_kernel(const float* __restrict__ outs, float* __restrict__ out) {
    int i = blockIdx.x * 256 + threadIdx.x;   // over T*H/4 float4s
    int t = i >> 8, c = i & 255;
    float4 a = ((const float4*)(outs + (size_t)(2 * t) * HDIM))[c];
    float4 b = ((const float4*)(outs + (size_t)(2 * t + 1) * HDIM))[c];
    float4 r;
    r.x = a.x + b.x; r.y = a.y + b.y; r.z = a.z + b.z; r.w = a.w + b.w;
    ((float4*)(out + (size_t)t * HDIM))[c] = r;
}

extern "C" void kernel_launch(void* const* d_in, const int* in_sizes, int n_in,
                              void* d_out, int out_size, void* d_ws, size_t ws_size,
                              hipStream_t stream) {
    const float* x  = (const float*)d_in[0];
    const float* rw = (const float*)d_in[1];
    const float* w1 = (const float*)d_in[2];
    const float* w3 = (const float*)d_in[3];
    const float* w2 = (const float*)d_in[4];
    float* out = (float*)d_out;
    char* ws = (char*)d_ws;

    int*   counts = (int*)(ws + OFF_COUNTS);
    int*   lists  = (int*)(ws + OFF_LISTS);
    float* wts    = (float*)(ws + OFF_WTS);
    bf16*  xb     = (bf16*)(ws + OFF_XB);
    bf16*  act    = (bf16*)(ws + OFF_ACT);
    float* outs   = (float*)(ws + OFF_OUTS);
    bf16*  wt1    = (bf16*)(ws + OFF_WT1);
    bf16*  wt3    = (bf16*)(ws + OFF_WT3);
    bf16*  wt2    = (bf16*)(ws + OFF_WT2);

    hipLaunchKernelGGL(moe_init_kernel, dim3(1), dim3(64), 0, stream, counts);
    hipLaunchKernelGGL(moe_transpose_kernel, dim3(512, 3, EXP), dim3(256), 0, stream,
                       w1, w3, w2, wt1, wt3, wt2);
    hipLaunchKernelGGL(moe_router_kernel, dim3(TTOK / 4), dim3(256), 0, stream,
                       x, rw, counts, lists, wts, xb);
    hipLaunchKernelGGL(moe_up_kernel, dim3(1024), dim3(256), 0, stream,
                       xb, wt1, wt3, counts, lists, act);
    hipLaunchKernelGGL(moe_down_kernel, dim3(512), dim3(256), 0, stream,
                       act, wt2, counts, lists, wts, outs);
    hipLaunchKernelGGL(moe_combine_kernel, dim3(TTOK * HDIM / 4 / 256), dim3(256), 0, stream,
                       outs, out);
}

// Round 9
// 371.655 us; speedup vs baseline: 4.6606x; 1.0834x over previous
//
#include <hip/hip_runtime.h>
#include <hip/hip_bf16.h>

#define TTOK 2048
#define HDIM 1024
#define EXP  8
#define FDIM 2048

typedef __attribute__((ext_vector_type(8))) short short8;
typedef __attribute__((ext_vector_type(4))) float f32x4;
typedef __hip_bfloat16 bf16;

// async global->LDS, 16B per lane; LDS dest is wave-uniform base + lane*16
#define GLOAD16(gp, lp) __builtin_amdgcn_global_load_lds( \
    (const __attribute__((address_space(1))) void*)(gp),  \
    (__attribute__((address_space(3))) void*)(lp), 16, 0, 0)

#define MFMA16(a, b, c) __builtin_amdgcn_mfma_f32_16x16x32_bf16((a), (b), (c), 0, 0, 0)

// workspace layout (bytes, 256-aligned)
#define OFF_COUNTS 0
#define OFF_LISTS  256
#define OFF_WTS    (OFF_LISTS + EXP * TTOK * 4)            // 65792
#define OFF_XB     (OFF_WTS + 2 * TTOK * 4)                // 82176
#define OFF_ACT    (OFF_XB + TTOK * HDIM * 2)              // 4276480
#define OFF_OUTS   (OFF_ACT + 2 * TTOK * FDIM * 2)         // 21053696
#define OFF_WT1    (OFF_OUTS + 2 * TTOK * HDIM * 4)        // 37830912
#define OFF_WT3    (OFF_WT1 + EXP * HDIM * FDIM * 2)       // 71385344
#define OFF_WT2    (OFF_WT3 + EXP * HDIM * FDIM * 2)       // 104939776
// end: 138494208 (~132 MB)

__global__ void moe_init_kernel(int* counts) {
    if (threadIdx.x < EXP) counts[threadIdx.x] = 0;
}

// one wave per token: fp32 logits, top-2, softmax, append slots; also x -> bf16
__global__ __launch_bounds__(256)
void moe_router_kernel(const float* __restrict__ x, const float* __restrict__ rw,
                       int* __restrict__ counts, int* __restrict__ lists,
                       float* __restrict__ wts, bf16* __restrict__ xb) {
    const int lane = threadIdx.x & 63;
    const int t = blockIdx.x * 4 + (threadIdx.x >> 6);
    const float* xr = x + (size_t)t * HDIM;
    bf16* xbr = xb + (size_t)t * HDIM;
    float acc[EXP];
#pragma unroll
    for (int e = 0; e < EXP; ++e) acc[e] = 0.f;
    for (int h = lane; h < HDIM; h += 64) {
        float xv = xr[h];
        xbr[h] = __float2bfloat16(xv);
#pragma unroll
        for (int e = 0; e < EXP; ++e) acc[e] = fmaf(xv, rw[h * EXP + e], acc[e]);
    }
#pragma unroll
    for (int e = 0; e < EXP; ++e)
        for (int off = 32; off > 0; off >>= 1) acc[e] += __shfl_xor(acc[e], off, 64);
    if (lane == 0) {
        int i0 = 0; float v0 = acc[0];
#pragma unroll
        for (int e = 1; e < EXP; ++e) if (acc[e] > v0) { v0 = acc[e]; i0 = e; }
        int i1 = -1; float v1 = -3.4e38f;
#pragma unroll
        for (int e = 0; e < EXP; ++e) if (e != i0 && acc[e] > v1) { v1 = acc[e]; i1 = e; }
        float ex = expf(v1 - v0);             // v1 <= v0, stable
        float w0 = 1.f / (1.f + ex);
        float w1v = ex / (1.f + ex);
        wts[t * 2 + 0] = w0;
        wts[t * 2 + 1] = w1v;
        int p0 = atomicAdd(&counts[i0], 1);
        lists[i0 * TTOK + p0] = t * 2 + 0;
        int p1 = atomicAdd(&counts[i1], 1);
        lists[i1 * TTOK + p1] = t * 2 + 1;
    }
}

// transpose+convert: wt[e][c][r] = bf16(w[e][r][c]); 64x64 tiles via padded fp32 LDS
__global__ __launch_bounds__(256)
void moe_transpose_kernel(const float* __restrict__ w1, const float* __restrict__ w3,
                          const float* __restrict__ w2, bf16* __restrict__ wt1,
                          bf16* __restrict__ wt3, bf16* __restrict__ wt2) {
    const int e = blockIdx.z, m = blockIdx.y;
    const float* src; bf16* dst; int R, C;
    if (m == 0)      { src = w1; dst = wt1; R = HDIM; C = FDIM; }
    else if (m == 1) { src = w3; dst = wt3; R = HDIM; C = FDIM; }
    else             { src = w2; dst = wt2; R = FDIM; C = HDIM; }
    const int Ct = C >> 6;
    const int tr = blockIdx.x / Ct, tc = blockIdx.x - tr * Ct;
    const int r0 = tr << 6, c0 = tc << 6;
    src += (size_t)e * R * C;
    dst += (size_t)e * R * C;
    __shared__ float Ls[64][65];
    const int tid = threadIdx.x;
    const int rr = tid >> 4, cg = tid & 15;
#pragma unroll
    for (int i = 0; i < 4; ++i) {
        const int r = rr + i * 16;
        float4 v = *(const float4*)(src + (size_t)(r0 + r) * C + c0 + cg * 4);
        Ls[cg * 4 + 0][r] = v.x;
        Ls[cg * 4 + 1][r] = v.y;
        Ls[cg * 4 + 2][r] = v.z;
        Ls[cg * 4 + 3][r] = v.w;
    }
    __syncthreads();
    const int fr = tid >> 2, ch = tid & 3;
    bf16 tmp[16] __attribute__((aligned(16)));
#pragma unroll
    for (int j = 0; j < 16; ++j) tmp[j] = __float2bfloat16(Ls[fr][ch * 16 + j]);
    bf16* dp = dst + (size_t)(c0 + fr) * R + r0 + ch * 16;
    *(short8*)(dp)     = *(short8*)&tmp[0];
    *(short8*)(dp + 8) = *(short8*)&tmp[8];
}

// gate/up GEMM: BM=128, BN=128, BK=64, 8 waves (4x2, wave-tile 32x64), 2-phase dbuf.
// Grid 1-D 1024: decoded so all m-blocks of one (f-tile,expert) B-panel share an XCD.
__global__ __launch_bounds__(512)
void moe_up_kernel(const bf16* __restrict__ xb, const bf16* __restrict__ wt1,
                   const bf16* __restrict__ wt3, const int* __restrict__ counts,
                   const int* __restrict__ lists, bf16* __restrict__ act) {
    const int b = blockIdx.x;
    const int xcd = b & 7, q = b >> 3;     // q 0..127
    const int pw = q >> 3, m = q & 7;      // pw 0..15
    const int p = pw * 8 + xcd;            // panel 0..127, xcd = p%8
    const int ft = p & 15, e = p >> 4;
    const int cnt = counts[e];
    const int tile0 = m * 128;
    if (tile0 >= cnt) return;
    const int f0 = ft * 128;

    const int tid = threadIdx.x;
    const int lane = tid & 63, w = tid >> 6;      // 8 waves
    const int wm = w >> 1, wn = w & 1;            // 4x2 wave grid
    const int l15 = lane & 15, kg = lane >> 4;
    const int lr = lane >> 3, lc = lane & 7;
    const int sc = (lc ^ lr) * 8;                 // swizzled source chunk (elements)

    __shared__ __align__(16) bf16 As0[128][64], As1[128][64];
    __shared__ __align__(16) bf16 B1s0[128][64], B1s1[128][64];
    __shared__ __align__(16) bf16 B3s0[128][64], B3s1[128][64];
    __shared__ int toks[128];
    __shared__ int srow[128];

    if (tid < 128) {
        int idx = tile0 + tid;
        int cl = idx < cnt ? idx : cnt - 1;
        int slot = lists[e * TTOK + cl];
        toks[tid] = slot >> 1;
        srow[tid] = (idx < cnt) ? slot : -1;
    }
    __syncthreads();

    size_t aoff[2];
#pragma unroll
    for (int j = 0; j < 2; ++j)
        aoff[j] = (size_t)toks[16 * w + 8 * j + lr] * HDIM + sc;
    const size_t ebase = (size_t)e * FDIM * HDIM;
    const size_t boff = ebase + (size_t)(f0 + 16 * w + lr) * HDIM + sc;

    f32x4 accg[2][4], accu[2][4];
#pragma unroll
    for (int mf = 0; mf < 2; ++mf)
#pragma unroll
        for (int nf = 0; nf < 4; ++nf) {
            accg[mf][nf] = (f32x4){0.f, 0.f, 0.f, 0.f};
            accu[mf][nf] = (f32x4){0.f, 0.f, 0.f, 0.f};
        }

    auto stage = [&](int k0, bf16 (*A)[64], bf16 (*B1)[64], bf16 (*B3)[64]) {
#pragma unroll
        for (int j = 0; j < 2; ++j) {
            GLOAD16(xb + aoff[j] + k0, &A[16 * w + 8 * j][0]);
            GLOAD16(wt1 + boff + (size_t)(8 * j) * HDIM + k0, &B1[16 * w + 8 * j][0]);
            GLOAD16(wt3 + boff + (size_t)(8 * j) * HDIM + k0, &B3[16 * w + 8 * j][0]);
        }
    };
    auto compute = [&](bf16 (*A)[64], bf16 (*B1)[64], bf16 (*B3)[64]) {
#pragma unroll
        for (int ks = 0; ks < 2; ++ks) {
            const int c = ((ks * 4 + kg) ^ (l15 & 7)) * 8;
            short8 af[2], b1f[4], b3f[4];
#pragma unroll
            for (int i = 0; i < 2; ++i)
                af[i] = *(const short8*)(&A[wm * 32 + i * 16 + l15][c]);
#pragma unroll
            for (int i = 0; i < 4; ++i) {
                b1f[i] = *(const short8*)(&B1[wn * 64 + i * 16 + l15][c]);
                b3f[i] = *(const short8*)(&B3[wn * 64 + i * 16 + l15][c]);
            }
#pragma unroll
            for (int mf = 0; mf < 2; ++mf)
#pragma unroll
                for (int nf = 0; nf < 4; ++nf) {
                    accg[mf][nf] = MFMA16(af[mf], b1f[nf], accg[mf][nf]);
                    accu[mf][nf] = MFMA16(af[mf], b3f[nf], accu[mf][nf]);
                }
        }
    };

    stage(0, As0, B1s0, B3s0);
    __syncthreads();                          // drain prologue loads
    for (int k0 = 0; k0 < HDIM; k0 += 128) {
        if (k0 + 64 < HDIM) stage(k0 + 64, As1, B1s1, B3s1);
        compute(As0, B1s0, B3s0);
        __syncthreads();                      // drains prefetch vmcnt + protects overwrite
        if (k0 + 128 < HDIM) stage(k0 + 128, As0, B1s0, B3s0);
        compute(As1, B1s1, B3s1);
        __syncthreads();
    }

    // epilogue: silu(g)*u -> act[slot, f]
#pragma unroll
    for (int mf = 0; mf < 2; ++mf) {
        const int rbase = wm * 32 + mf * 16 + kg * 4;
#pragma unroll
        for (int r = 0; r < 4; ++r) {
            const int slot = srow[rbase + r];
            if (slot < 0) continue;
#pragma unroll
            for (int nf = 0; nf < 4; ++nf) {
                float g = accg[mf][nf][r], u = accu[mf][nf][r];
                float s = g / (1.f + expf(-g));
                act[(size_t)slot * FDIM + f0 + wn * 64 + nf * 16 + l15] = __float2bfloat16(s * u);
            }
        }
    }
}

// down GEMM: BM=128, BN=128, BK=64, 8 waves, 2-phase dbuf; outs = wts * (act @ wt2^T)
__global__ __launch_bounds__(512)
void moe_down_kernel(const bf16* __restrict__ act, const bf16* __restrict__ wt2,
                     const int* __restrict__ counts, const int* __restrict__ lists,
                     const float* __restrict__ wts, float* __restrict__ outs) {
    const int b = blockIdx.x;
    const int xcd = b & 7, q = b >> 3;     // q 0..63
    const int pw = q >> 3, m = q & 7;      // pw 0..7
    const int p = pw * 8 + xcd;            // panel 0..63
    const int ht = p & 7, e = p >> 3;
    const int cnt = counts[e];
    const int tile0 = m * 128;
    if (tile0 >= cnt) return;
    const int h0 = ht * 128;

    const int tid = threadIdx.x;
    const int lane = tid & 63, w = tid >> 6;
    const int wm = w >> 1, wn = w & 1;
    const int l15 = lane & 15, kg = lane >> 4;
    const int lr = lane >> 3, lc = lane & 7;
    const int sc = (lc ^ lr) * 8;

    __shared__ __align__(16) bf16 As0[128][64], As1[128][64];
    __shared__ __align__(16) bf16 Bs0[128][64], Bs1[128][64];
    __shared__ int toks[128];
    __shared__ int srow[128];

    if (tid < 128) {
        int idx = tile0 + tid;
        int cl = idx < cnt ? idx : cnt - 1;
        int slot = lists[e * TTOK + cl];
        toks[tid] = slot;
        srow[tid] = (idx < cnt) ? slot : -1;
    }
    __syncthreads();

    size_t aoff[2];
#pragma unroll
    for (int j = 0; j < 2; ++j)
        aoff[j] = (size_t)toks[16 * w + 8 * j + lr] * FDIM + sc;
    const size_t ebase = (size_t)e * FDIM * HDIM;
    const size_t boff = ebase + (size_t)(h0 + 16 * w + lr) * FDIM + sc;

    f32x4 acc[2][4];
#pragma unroll
    for (int mf = 0; mf < 2; ++mf)
#pragma unroll
        for (int nf = 0; nf < 4; ++nf) acc[mf][nf] = (f32x4){0.f, 0.f, 0.f, 0.f};

    auto stage = [&](int k0, bf16 (*A)[64], bf16 (*B)[64]) {
#pragma unroll
        for (int j = 0; j < 2; ++j) {
            GLOAD16(act + aoff[j] + k0, &A[16 * w + 8 * j][0]);
            GLOAD16(wt2 + boff + (size_t)(8 * j) * FDIM + k0, &B[16 * w + 8 * j][0]);
        }
    };
    auto compute = [&](bf16 (*A)[64], bf16 (*B)[64]) {
#pragma unroll
        for (int ks = 0; ks < 2; ++ks) {
            const int c = ((ks * 4 + kg) ^ (l15 & 7)) * 8;
            short8 af[2], bf[4];
#pragma unroll
            for (int i = 0; i < 2; ++i)
                af[i] = *(const short8*)(&A[wm * 32 + i * 16 + l15][c]);
#pragma unroll
            for (int i = 0; i < 4; ++i)
                bf[i] = *(const short8*)(&B[wn * 64 + i * 16 + l15][c]);
#pragma unroll
            for (int mf = 0; mf < 2; ++mf)
#pragma unroll
                for (int nf = 0; nf < 4; ++nf)
                    acc[mf][nf] = MFMA16(af[mf], bf[nf], acc[mf][nf]);
        }
    };

    stage(0, As0, Bs0);
    __syncthreads();
    for (int k0 = 0; k0 < FDIM; k0 += 128) {
        if (k0 + 64 < FDIM) stage(k0 + 64, As1, Bs1);
        compute(As0, Bs0);
        __syncthreads();
        if (k0 + 128 < FDIM) stage(k0 + 128, As0, Bs0);
        compute(As1, Bs1);
        __syncthreads();
    }

#pragma unroll
    for (int mf = 0; mf < 2; ++mf) {
        const int rbase = wm * 32 + mf * 16 + kg * 4;
#pragma unroll
        for (int r = 0; r < 4; ++r) {
            const int slot = srow[rbase + r];
            if (slot < 0) continue;
            const float wgt = wts[slot];
#pragma unroll
            for (int nf = 0; nf < 4; ++nf)
                outs[(size_t)slot * HDIM + h0 + wn * 64 + nf * 16 + l15] = acc[mf][nf][r] * wgt;
        }
    }
}

// out[t] = outs[2t] + outs[2t+1]
__global__ __launch_bounds__(256)
void moe_combine_kernel(const float* __restrict__ outs, float* __restrict__ out) {
    int i = blockIdx.x * 256 + threadIdx.x;   // over T*H/4 float4s
    int t = i >> 8, c = i & 255;
    float4 a = ((const float4*)(outs + (size_t)(2 * t) * HDIM))[c];
    float4 b = ((const float4*)(outs + (size_t)(2 * t + 1) * HDIM))[c];
    float4 r;
    r.x = a.x + b.x; r.y = a.y + b.y; r.z = a.z + b.z; r.w = a.w + b.w;
    ((float4*)(out + (size_t)t * HDIM))[c] = r;
}

extern "C" void kernel_launch(void* const* d_in, const int* in_sizes, int n_in,
                              void* d_out, int out_size, void* d_ws, size_t ws_size,
                              hipStream_t stream) {
    const float* x  = (const float*)d_in[0];
    const float* rw = (const float*)d_in[1];
    const float* w1 = (const float*)d_in[2];
    const float* w3 = (const float*)d_in[3];
    const float* w2 = (const float*)d_in[4];
    float* out = (float*)d_out;
    char* ws = (char*)d_ws;

    int*   counts = (int*)(ws + OFF_COUNTS);
    int*   lists  = (int*)(ws + OFF_LISTS);
    float* wts    = (float*)(ws + OFF_WTS);
    bf16*  xb     = (bf16*)(ws + OFF_XB);
    bf16*  act    = (bf16*)(ws + OFF_ACT);
    float* outs   = (float*)(ws + OFF_OUTS);
    bf16*  wt1    = (bf16*)(ws + OFF_WT1);
    bf16*  wt3    = (bf16*)(ws + OFF_WT3);
    bf16*  wt2    = (bf16*)(ws + OFF_WT2);

    hipLaunchKernelGGL(moe_init_kernel, dim3(1), dim3(64), 0, stream, counts);
    hipLaunchKernelGGL(moe_transpose_kernel, dim3(512, 3, EXP), dim3(256), 0, stream,
                       w1, w3, w2, wt1, wt3, wt2);
    hipLaunchKernelGGL(moe_router_kernel, dim3(TTOK / 4), dim3(256), 0, stream,
                       x, rw, counts, lists, wts, xb);
    hipLaunchKernelGGL(moe_up_kernel, dim3(1024), dim3(512), 0, stream,
                       xb, wt1, wt3, counts, lists, act);
    hipLaunchKernelGGL(moe_down_kernel, dim3(512), dim3(512), 0, stream,
                       act, wt2, counts, lists, wts, outs);
    hipLaunchKernelGGL(moe_combine_kernel, dim3(TTOK * HDIM / 4 / 256), dim3(256), 0, stream,
                       outs, out);
}